// Round 3
// baseline (724.156 us; speedup 1.0000x reference)
//
#include <hip/hip_runtime.h>

#define NB 50          // bins
#define DD 512         // feature dim
#define KSZ 5
#define SORT_ROWS 4096     // rows per sort block
#define EPT 16             // elements per thread in sort (4096/256)
#define RPC 64             // rows per reduce chunk (one wave per chunk)
#define UNR 8              // reduce inner unroll (rows per batch)

// ---------------------------------------------------------------------------
// Pass 0: block-local counting sort of labels (unchanged from round 2).
// ---------------------------------------------------------------------------
__global__ __launch_bounds__(256) void fds_sort(
    const int* __restrict__ labels,
    int*       __restrict__ packed,   // [N], (row<<6)|lab, grouped by bin per block
    float*     __restrict__ g_cnt)    // [NB]
{
    __shared__ int s_hist[NB];
    __shared__ int s_cur[NB];
    const int tid  = threadIdx.x;
    const int base = blockIdx.x * SORT_ROWS;

    if (tid < NB) s_hist[tid] = 0;
    __syncthreads();

    int lab[EPT];
#pragma unroll
    for (int j = 0; j < EPT; ++j) {
        lab[j] = labels[base + j * 256 + tid];          // coalesced
        __hip_atomic_fetch_add(&s_hist[lab[j]], 1,
                               __ATOMIC_RELAXED, __HIP_MEMORY_SCOPE_WORKGROUP);
    }
    __syncthreads();

    if (tid == 0) {
        int run = 0;
        for (int b = 0; b < NB; ++b) { s_cur[b] = run; run += s_hist[b]; }
    }
    __syncthreads();

    if (tid < NB)
        __hip_atomic_fetch_add(&g_cnt[tid], (float)s_hist[tid],
                               __ATOMIC_RELAXED, __HIP_MEMORY_SCOPE_AGENT);

#pragma unroll
    for (int j = 0; j < EPT; ++j) {
        const int l   = lab[j];
        const int pos = __hip_atomic_fetch_add(&s_cur[l], 1,
                              __ATOMIC_RELAXED, __HIP_MEMORY_SCOPE_WORKGROUP);
        const int row = base + j * 256 + tid;
        packed[base + pos] = (row << 6) | l;
    }
}

// ---------------------------------------------------------------------------
// Pass 1: full-row gather-reduce. One wave owns 64 sorted rows x all 512
// columns: lane covers cols [lane*4, lane*4+4) and [256+lane*4, ...).
// Row index is made wave-uniform via readfirstlane -> scalar base address,
// loop-invariant lane offset, 2 KB contiguous per row. Flush to global fp
// atomics only on (scalar-branch) label change (~2-3x per chunk).
// ---------------------------------------------------------------------------
__global__ __launch_bounds__(256) void fds_reduce(
    const float* __restrict__ features,
    const int*   __restrict__ packed,
    float* __restrict__ g_sum,
    float* __restrict__ g_sq)
{
    const int tid  = threadIdx.x;
    const int wave = tid >> 6;
    const int lane = tid & 63;
    const int chunk = blockIdx.x * 4 + wave;    // 0..4095
    const int r0 = chunk * RPC;
    const int c0 = lane * 4;

    float4 s0 = {0,0,0,0}, s1 = {0,0,0,0};
    float4 q0 = {0,0,0,0}, q1 = {0,0,0,0};

    int pk[UNR];
#pragma unroll
    for (int j = 0; j < UNR; ++j)
        pk[j] = __builtin_amdgcn_readfirstlane(packed[r0 + j]);
    int cur = pk[0] & 63;

    for (int it = 0; it < RPC; it += UNR) {
        // feature loads for current batch (scalar base + lane offset)
        float4 v0[UNR], v1[UNR];
#pragma unroll
        for (int j = 0; j < UNR; ++j) {
            const float* rp = features + (size_t)(pk[j] >> 6) * DD;
            v0[j] = *(const float4*)(rp + c0);
            v1[j] = *(const float4*)(rp + 256 + c0);
        }

        // prefetch next batch of packed entries
        int pk2[UNR];
        const int nb = (it + UNR < RPC) ? (r0 + it + UNR) : r0;
#pragma unroll
        for (int j = 0; j < UNR; ++j)
            pk2[j] = __builtin_amdgcn_readfirstlane(packed[nb + j]);

#pragma unroll
        for (int j = 0; j < UNR; ++j) {
            const int l = pk[j] & 63;           // scalar
            if (l != cur) {                     // scalar branch
                float* ps = &g_sum[cur * DD + c0];
                float* pq = &g_sq [cur * DD + c0];
#pragma unroll
                for (int k = 0; k < 4; ++k) {
                    __hip_atomic_fetch_add(ps + k,       (&s0.x)[k], __ATOMIC_RELAXED, __HIP_MEMORY_SCOPE_AGENT);
                    __hip_atomic_fetch_add(ps + 256 + k, (&s1.x)[k], __ATOMIC_RELAXED, __HIP_MEMORY_SCOPE_AGENT);
                    __hip_atomic_fetch_add(pq + k,       (&q0.x)[k], __ATOMIC_RELAXED, __HIP_MEMORY_SCOPE_AGENT);
                    __hip_atomic_fetch_add(pq + 256 + k, (&q1.x)[k], __ATOMIC_RELAXED, __HIP_MEMORY_SCOPE_AGENT);
                }
                s0 = {0,0,0,0}; s1 = {0,0,0,0};
                q0 = {0,0,0,0}; q1 = {0,0,0,0};
                cur = l;
            }
#pragma unroll
            for (int k = 0; k < 4; ++k) {
                (&s0.x)[k] += (&v0[j].x)[k];
                (&q0.x)[k] = fmaf((&v0[j].x)[k], (&v0[j].x)[k], (&q0.x)[k]);
                (&s1.x)[k] += (&v1[j].x)[k];
                (&q1.x)[k] = fmaf((&v1[j].x)[k], (&v1[j].x)[k], (&q1.x)[k]);
            }
        }
#pragma unroll
        for (int j = 0; j < UNR; ++j) pk[j] = pk2[j];
    }

    // final flush
    {
        float* ps = &g_sum[cur * DD + c0];
        float* pq = &g_sq [cur * DD + c0];
#pragma unroll
        for (int k = 0; k < 4; ++k) {
            __hip_atomic_fetch_add(ps + k,       (&s0.x)[k], __ATOMIC_RELAXED, __HIP_MEMORY_SCOPE_AGENT);
            __hip_atomic_fetch_add(ps + 256 + k, (&s1.x)[k], __ATOMIC_RELAXED, __HIP_MEMORY_SCOPE_AGENT);
            __hip_atomic_fetch_add(pq + k,       (&q0.x)[k], __ATOMIC_RELAXED, __HIP_MEMORY_SCOPE_AGENT);
            __hip_atomic_fetch_add(pq + 256 + k, (&q1.x)[k], __ATOMIC_RELAXED, __HIP_MEMORY_SCOPE_AGENT);
        }
    }
}

// ---------------------------------------------------------------------------
// Pass 2: finalize (unchanged — verified correct).
// out layout: new_mean[25600] | new_var[25600] | new_num[50]
//             | smoothed_mean[25600] | smoothed_var[25600]
// ---------------------------------------------------------------------------
__global__ __launch_bounds__(256) void fds_finalize(
    const float* __restrict__ g_sum, const float* __restrict__ g_sq,
    const float* __restrict__ g_cnt,
    const float* __restrict__ running_mean, const float* __restrict__ running_var,
    const float* __restrict__ num_tracked, const float* __restrict__ kwin,
    float* __restrict__ out)
{
    __shared__ float s_cnt[NB];
    __shared__ float s_w[KSZ];
    const int tid = threadIdx.x;
    if (tid < NB)  s_cnt[tid] = g_cnt[tid];
    if (tid < KSZ) s_w[tid]   = kwin[tid];
    __syncthreads();

    const int idx = blockIdx.x * 256 + tid;   // 0..25599 (grid exactly 100)
    const int b = idx / DD;
    const int d = idx - b * DD;

    float sm = 0.f, sv = 0.f, my_nm = 0.f, my_nv = 0.f;
#pragma unroll
    for (int k = 0; k < KSZ; ++k) {
        const int i = b + k;
        const int bb = (i < 2) ? (2 - i) : ((i >= NB + 2) ? (2 * NB - i) : (i - 2));
        const float cnt    = s_cnt[bb];
        const float safe_n = fmaxf(cnt, 1.f);
        const float s   = g_sum[bb * DD + d];
        const float sqv = g_sq [bb * DD + d];
        const float mean = s / safe_n;
        const float var  = (sqv - safe_n * mean * mean) / fmaxf(cnt - 1.f, 1.f);
        const float rm = running_mean[bb * DD + d];
        const float rv = running_var [bb * DD + d];
        float nm, nv;
        if (cnt > 0.f) {
            nm = 0.1f * mean + 0.9f * rm;
            nv = 0.1f * var  + 0.9f * rv;
        } else {
            nm = rm; nv = rv;
        }
        sm += s_w[k] * nm;
        sv += s_w[k] * nv;
        if (k == 2) { my_nm = nm; my_nv = nv; }
    }
    out[idx]                    = my_nm;
    out[NB * DD + idx]          = my_nv;
    out[2 * NB * DD + NB + idx] = sm;
    out[3 * NB * DD + NB + idx] = sv;
    if (idx < NB)
        out[2 * NB * DD + idx] = num_tracked[idx] + s_cnt[idx];
}

extern "C" void kernel_launch(void* const* d_in, const int* in_sizes, int n_in,
                              void* d_out, int out_size, void* d_ws, size_t ws_size,
                              hipStream_t stream)
{
    const float* features     = (const float*)d_in[0];
    const int*   labels       = (const int*)  d_in[1];
    const float* running_mean = (const float*)d_in[2];
    const float* running_var  = (const float*)d_in[3];
    const float* num_tracked  = (const float*)d_in[4];
    const float* kwin         = (const float*)d_in[5];
    float* out = (float*)d_out;

    const int N = in_sizes[1];   // 262144 rows

    // ws layout: g_sum[25600] | g_sq[25600] | g_cnt[50] | packed[N]
    float* g_sum  = (float*)d_ws;
    float* g_sq   = g_sum + NB * DD;
    float* g_cnt  = g_sq  + NB * DD;
    int*   packed = (int*)(g_cnt + NB);

    hipMemsetAsync(d_ws, 0, (size_t)(2 * NB * DD + NB) * sizeof(float), stream);

    fds_sort<<<N / SORT_ROWS, 256, 0, stream>>>(labels, packed, g_cnt);

    fds_reduce<<<N / RPC / 4, 256, 0, stream>>>(features, packed, g_sum, g_sq);

    fds_finalize<<<NB * DD / 256, 256, 0, stream>>>(
        g_sum, g_sq, g_cnt, running_mean, running_var, num_tracked, kwin, out);
}